// Round 11
// baseline (584.814 us; speedup 1.0000x reference)
//
#include <hip/hip_runtime.h>
#include <hip/hip_bf16.h>
#include <hip/hip_cooperative_groups.h>
#include <stdint.h>

namespace cg = cooperative_groups;

#define NN 10000
#define NE 250000
#define FEAT 16
#define EMB 32
#define HID 32
#define NV 12
#define EAD 9
#define NG 64
#define EPB 128   // edges per virtual block in edge phase
#define NCH 25    // nodes per virtual block in computeQ phase

__device__ __forceinline__ uint32_t bf16rne(float f) {
    uint32_t u = __float_as_uint(f);
    return (u + 0x7fffu + ((u >> 16) & 1u)) >> 16;
}
__device__ __forceinline__ float blo(uint32_t p) { return __uint_as_float(p << 16); }
__device__ __forceinline__ float bhi(uint32_t p) { return __uint_as_float(p & 0xffff0000u); }

// ---------------------------------------------------------------------------
// Prepass kernels (ordinary dispatches; measured fast)
// ---------------------------------------------------------------------------
__global__ void edge_stats_kernel(const int* __restrict__ src,
                                  const int* __restrict__ dst,
                                  int* __restrict__ histS,
                                  int* __restrict__ histD) {
    int e = blockIdx.x * blockDim.x + threadIdx.x;
    if (e >= NE) return;
    atomicAdd(&histS[src[e]], 1);
    atomicAdd(&histD[dst[e]], 1);
}

__global__ __launch_bounds__(1024) void scan_kernel(const int* __restrict__ hist,
                                                    int* __restrict__ rowStart,
                                                    int* __restrict__ cursor) {
    __shared__ int part[1024];
    int t = threadIdx.x;
    int base = t * 10;
    int local[10];
    int s = 0;
#pragma unroll
    for (int i = 0; i < 10; ++i) {
        int v = (base + i < NN) ? hist[base + i] : 0;
        local[i] = s;
        s += v;
    }
    part[t] = s;
    __syncthreads();
    for (int off = 1; off < 1024; off <<= 1) {
        int v = (t >= off) ? part[t - off] : 0;
        __syncthreads();
        part[t] += v;
        __syncthreads();
    }
    int pre = (t == 0) ? 0 : part[t - 1];
#pragma unroll
    for (int i = 0; i < 10; ++i) {
        if (base + i < NN) {
            int rs = pre + local[i];
            rowStart[base + i] = rs;
            cursor[base + i] = rs;
        }
    }
    if (t == 1023) rowStart[NN] = part[1023];
}

__global__ void scatter_kernel(const float* __restrict__ ea,
                               const int* __restrict__ src,
                               const int* __restrict__ dst,
                               int* __restrict__ cursorS,
                               float* __restrict__ ea_p,   // [E,12]
                               int* __restrict__ src_s,
                               int* __restrict__ dst_s) {
    int e = blockIdx.x * blockDim.x + threadIdx.x;
    if (e >= NE) return;
    int sv = src[e];
    int pos = atomicAdd(&cursorS[sv], 1);
    src_s[pos] = sv;
    dst_s[pos] = dst[e];
#pragma unroll
    for (int j = 0; j < 12; ++j)
        ea_p[(size_t)pos * 12 + j] = (j < EAD) ? ea[(size_t)e * EAD + j] : 0.f;
}

// ---------------------------------------------------------------------------
// Phase device functions (all grid-stride; shared 8.3KB LDS buffer)
// ---------------------------------------------------------------------------
struct Params {
    const float* x; const float* ea_p;
    const int* src_s; const int* dst_s; const int* histD; const int* batch;
    const float* nn1_w1; const float* nn1_b1; const float* nn1_w2; const float* nn1_b2;
    const float* root1; const float* bias1;
    const float* nn2_w1; const float* nn2_b1; const float* nn2_w2; const float* nn2_b2;
    const float* root2; const float* bias2;
    const float* lin_w; const float* lin_b;
    uint32_t* Qp; float* Qb; float* agg; float* h1; float* h2;
    float* pooled; float* gcnt; float* out;
};

// Qp[n][kk][o] = packed bf16 pair of Q[n,2kk,o]/Q[n,2kk+1,o]; kk==0 lanes also
// emit fp32 bias row Qb. h rows staged in LDS (vector loads; no scalar-cache
// reliance across grid.sync).
template <int DIN>
__device__ void computeQ_phase(const float* __restrict__ h,
                               const float* __restrict__ w2,
                               const float* __restrict__ b2,
                               uint32_t* __restrict__ Qp,
                               float* __restrict__ Qb,
                               float* smem) {
    int t = threadIdx.x;
    int o = t & 31;
    const int NVB = (NN / NCH) * 2;   // 800
    for (int vb = blockIdx.x; vb < NVB; vb += gridDim.x) {
        int nb = vb >> 1;
        int kk = (vb & 1) * 8 + (t >> 5);   // 0..15
        int n0 = nb * NCH;
        __syncthreads();
        for (int idx = t; idx < NCH * DIN; idx += 256)
            smem[idx] = h[(size_t)n0 * DIN + idx];
        __syncthreads();
        float w0[DIN], w1r[DIN];
        const float* wa = w2 + (size_t)(2 * kk) * (DIN * 32) + o;
        const float* wb = w2 + (size_t)(2 * kk + 1) * (DIN * 32) + o;
#pragma unroll
        for (int i = 0; i < DIN; ++i) { w0[i] = wa[i * 32]; w1r[i] = wb[i * 32]; }
        for (int j = 0; j < NCH; ++j) {
            const float* sh = smem + j * DIN;
            float s0 = 0.f, s1 = 0.f;
#pragma unroll
            for (int i4 = 0; i4 < DIN / 4; ++i4) {
                float4 hv = *(const float4*)(sh + i4 * 4);
                s0 += hv.x * w0[4*i4] + hv.y * w0[4*i4+1] + hv.z * w0[4*i4+2] + hv.w * w0[4*i4+3];
                s1 += hv.x * w1r[4*i4] + hv.y * w1r[4*i4+1] + hv.z * w1r[4*i4+2] + hv.w * w1r[4*i4+3];
            }
            int n = n0 + j;
            Qp[((size_t)n * 16 + kk) * 32 + o] = (bf16rne(s1) << 16) | bf16rne(s0);
            if (kk == 0) {
                float sb = 0.f;
#pragma unroll
                for (int i = 0; i < DIN; ++i) sb += sh[i] * b2[i * 32 + o];
                Qb[(size_t)n * 32 + o] = sb;
            }
        }
    }
}

// 32 lanes/edge: edge-MLP (3x float4), hidden via wave LDS broadcast, Q
// gathered as bf16 pairs (src-sorted), atomicAdd into agg[dst].
__device__ void edge_phase(const float* __restrict__ ea_p,
                           const int* __restrict__ src_s,
                           const int* __restrict__ dst_s,
                           const float* __restrict__ w1,
                           const float* __restrict__ b1,
                           const uint32_t* __restrict__ Qp,
                           const float* __restrict__ Qb,
                           float* __restrict__ agg,
                           float* smem) {
    float* s_hid = smem;   // [8][32]
    int t = threadIdx.x;
    int o = t & 31;
    int slot = t >> 5;
    float w1r[EAD];
#pragma unroll
    for (int j = 0; j < EAD; ++j) w1r[j] = w1[j * 32 + o];
    float b1r = b1[o];

    const int NCHK = (NE + EPB - 1) / EPB;
    for (int vb = blockIdx.x; vb < NCHK; vb += gridDim.x) {
        int base = vb * EPB, eend = min(base + EPB, NE);
        for (int e = base + slot; e < eend; e += 8) {
            const float4* eav = (const float4*)(ea_p + (size_t)e * 12);
            float4 a0 = eav[0], a1 = eav[1], a2 = eav[2];
            float hs = b1r;
            hs += a0.x * w1r[0] + a0.y * w1r[1] + a0.z * w1r[2] + a0.w * w1r[3];
            hs += a1.x * w1r[4] + a1.y * w1r[5] + a1.z * w1r[6] + a1.w * w1r[7];
            hs += a2.x * w1r[8];
            float hd = fmaxf(hs, 0.f);

            s_hid[slot * 32 + o] = hd;
            __builtin_amdgcn_wave_barrier();

            int sv = src_s[e];
            const uint32_t* q = Qp + (size_t)sv * 512 + o;
            float m = Qb[(size_t)sv * 32 + o];
            const float4* hq = (const float4*)(s_hid + slot * 32);
#pragma unroll
            for (int c = 0; c < 8; ++c) {
                float4 hv = hq[c];
                uint32_t qa  = q[(2 * c) * 32];
                uint32_t qb2 = q[(2 * c + 1) * 32];
                m += hv.x * blo(qa) + hv.y * bhi(qa)
                   + hv.z * blo(qb2) + hv.w * bhi(qb2);
            }
            atomicAdd(&agg[(size_t)dst_s[e] * 32 + o], m);
            __builtin_amdgcn_wave_barrier();
        }
    }
}

// Node update: 32 nodes per virtual block; root + h staged in LDS; re-zeros
// agg for the next conv / next call.
template <int DIN, bool POOL>
__device__ void node_phase(float* __restrict__ agg,
                           const int* __restrict__ histD,
                           const float* __restrict__ hin,
                           const float* __restrict__ root,
                           const float* __restrict__ bias,
                           float* __restrict__ hout,
                           float* __restrict__ pooled,
                           const int* __restrict__ batch,
                           float* __restrict__ gcnt,
                           float* smem) {
    float* s_root = smem;                 // DIN*32
    float* s_h    = smem + DIN * 32;      // 32*(DIN+1)
    int t = threadIdx.x;
    const int NVB = (NN + 31) / 32;       // 313
    for (int vb = blockIdx.x; vb < NVB; vb += gridDim.x) {
        int n0 = vb * 32;
        __syncthreads();
        for (int i = t; i < DIN * 8; i += 256)
            ((float4*)s_root)[i] = ((const float4*)root)[i];
        for (int idx = t; idx < 32 * DIN; idx += 256) {
            int nl = idx / DIN, i = idx - nl * DIN;
            int n = n0 + nl;
            s_h[nl * (DIN + 1) + i] = (n < NN) ? hin[(size_t)n * DIN + i] : 0.f;
        }
        __syncthreads();
        int nl = t >> 3, cg4 = t & 7;
        int n = n0 + nl;
        if (n < NN) {
            float inv = 1.0f / fmaxf((float)histD[n], 1.0f);
            float* ap = agg + (size_t)n * 32 + cg4 * 4;
            float4 a4 = *(const float4*)ap;
            *(float4*)ap = make_float4(0.f, 0.f, 0.f, 0.f);  // re-zero
            float4 b4 = *(const float4*)(bias + cg4 * 4);
            float4 s;
            s.x = a4.x * inv + b4.x;
            s.y = a4.y * inv + b4.y;
            s.z = a4.z * inv + b4.z;
            s.w = a4.w * inv + b4.w;
#pragma unroll
            for (int i = 0; i < DIN; ++i) {
                float hv = s_h[nl * (DIN + 1) + i];
                float4 r4 = *(const float4*)(s_root + i * 32 + cg4 * 4);
                s.x += hv * r4.x; s.y += hv * r4.y; s.z += hv * r4.z; s.w += hv * r4.w;
            }
            s.x = fmaxf(s.x, 0.f); s.y = fmaxf(s.y, 0.f);
            s.z = fmaxf(s.z, 0.f); s.w = fmaxf(s.w, 0.f);
            *(float4*)(hout + (size_t)n * 32 + cg4 * 4) = s;
            if (POOL) {
                int g = batch[n];
                atomicAdd(&pooled[g * 32 + cg4 * 4 + 0], s.x);
                atomicAdd(&pooled[g * 32 + cg4 * 4 + 1], s.y);
                atomicAdd(&pooled[g * 32 + cg4 * 4 + 2], s.z);
                atomicAdd(&pooled[g * 32 + cg4 * 4 + 3], s.w);
                if (cg4 == 0) atomicAdd(&gcnt[g], 1.0f);
            }
        }
    }
}

__device__ void final_phase(const float* __restrict__ pooled,
                            const float* __restrict__ gcnt,
                            const float* __restrict__ lin_w,
                            const float* __restrict__ lin_b,
                            float* __restrict__ out) {
    int g = threadIdx.x;
    if (g >= NG) return;
    float inv = 1.0f / fmaxf(gcnt[g], 1.0f);
    float p[HID];
#pragma unroll
    for (int h = 0; h < HID; ++h) p[h] = pooled[g * HID + h] * inv;
    float logits[NV];
    float mx = -1e30f;
#pragma unroll
    for (int v = 0; v < NV; ++v) {
        float s = lin_b[v];
#pragma unroll
        for (int h = 0; h < HID; ++h) s += p[h] * lin_w[h * NV + v];
        logits[v] = s;
        mx = fmaxf(mx, s);
    }
    float se = 0.f;
#pragma unroll
    for (int v = 0; v < NV; ++v) se += expf(logits[v] - mx);
    float lse = mx + logf(se);
#pragma unroll
    for (int v = 0; v < NV; ++v) out[g * NV + v] = logits[v] - lse;
}

// ---------------------------------------------------------------------------
// Cooperative mega-kernel: all data-dependent phases, one dispatch.
// ---------------------------------------------------------------------------
__global__ __launch_bounds__(256) void mega_kernel(Params P) {
    __shared__ __align__(16) float smem[2080];   // 8320 B, reused per phase
    cg::grid_group grid = cg::this_grid();

    computeQ_phase<FEAT>(P.x, P.nn1_w2, P.nn1_b2, P.Qp, P.Qb, smem);
    grid.sync();
    edge_phase(P.ea_p, P.src_s, P.dst_s, P.nn1_w1, P.nn1_b1, P.Qp, P.Qb, P.agg, smem);
    grid.sync();
    node_phase<FEAT, false>(P.agg, P.histD, P.x, P.root1, P.bias1, P.h1,
                            nullptr, nullptr, nullptr, smem);
    grid.sync();
    computeQ_phase<EMB>(P.h1, P.nn2_w2, P.nn2_b2, P.Qp, P.Qb, smem);
    grid.sync();
    edge_phase(P.ea_p, P.src_s, P.dst_s, P.nn2_w1, P.nn2_b1, P.Qp, P.Qb, P.agg, smem);
    grid.sync();
    node_phase<EMB, true>(P.agg, P.histD, P.h1, P.root2, P.bias2, P.h2,
                          P.pooled, P.batch, P.gcnt, smem);
    grid.sync();
    if (blockIdx.x == 0) final_phase(P.pooled, P.gcnt, P.lin_w, P.lin_b, P.out);
}

// Fallback: same phases as ordinary dispatches (if coop launch refused).
__global__ __launch_bounds__(256) void phase_kernel(Params P, int ph) {
    __shared__ __align__(16) float smem[2080];
    switch (ph) {
    case 0: computeQ_phase<FEAT>(P.x, P.nn1_w2, P.nn1_b2, P.Qp, P.Qb, smem); break;
    case 1: edge_phase(P.ea_p, P.src_s, P.dst_s, P.nn1_w1, P.nn1_b1, P.Qp, P.Qb, P.agg, smem); break;
    case 2: node_phase<FEAT, false>(P.agg, P.histD, P.x, P.root1, P.bias1, P.h1,
                                    nullptr, nullptr, nullptr, smem); break;
    case 3: computeQ_phase<EMB>(P.h1, P.nn2_w2, P.nn2_b2, P.Qp, P.Qb, smem); break;
    case 4: edge_phase(P.ea_p, P.src_s, P.dst_s, P.nn2_w1, P.nn2_b1, P.Qp, P.Qb, P.agg, smem); break;
    case 5: node_phase<EMB, true>(P.agg, P.histD, P.h1, P.root2, P.bias2, P.h2,
                                  P.pooled, P.batch, P.gcnt, smem); break;
    case 6: if (blockIdx.x == 0) final_phase(P.pooled, P.gcnt, P.lin_w, P.lin_b, P.out); break;
    }
}

// ---------------------------------------------------------------------------
extern "C" void kernel_launch(void* const* d_in, const int* in_sizes, int n_in,
                              void* d_out, int out_size, void* d_ws, size_t ws_size,
                              hipStream_t stream) {
    const float* x      = (const float*)d_in[0];
    const float* ea     = (const float*)d_in[1];
    const int*   eidx   = (const int*)d_in[2];
    const int*   batch  = (const int*)d_in[3];

    const int* src = eidx;
    const int* dst = eidx + NE;

    // workspace layout (same as round 10)
    char* base = (char*)d_ws;
    uint32_t* Qp   = (uint32_t*)base;                       // NN*512
    float* ea_p    = (float*)(Qp + (size_t)NN * 512);       // NE*12
    float* Qb      = ea_p + (size_t)NE * 12;                // NN*32
    float* h1      = Qb + (size_t)NN * 32;                  // NN*32
    float* h2      = h1 + (size_t)NN * 32;                  // NN*32
    float* agg     = h2 + (size_t)NN * 32;                  // NN*32 (zeroed)
    int*   src_s   = (int*)(agg + (size_t)NN * 32);         // NE
    int*   dst_s   = src_s + NE;                            // NE
    int*   rowS    = dst_s + NE;                            // NN+1
    int*   curS    = rowS + NN + 1;                         // NN
    int*   histS   = curS + NN;                             // NN (zeroed from here)
    int*   histD   = histS + NN;                            // NN
    float* pooled  = (float*)(histD + NN);                  // NG*32
    float* gcnt    = pooled + NG * 32;                      // NG
    size_t zero_bytes = ((size_t)NN * 2 + NG * 32 + NG) * 4;

    hipMemsetAsync(agg, 0, (size_t)NN * 32 * sizeof(float), stream);
    hipMemsetAsync(histS, 0, zero_bytes, stream);

    // ---- prepass: src-sort + degree histograms ----
    edge_stats_kernel<<<(NE + 255) / 256, 256, 0, stream>>>(src, dst, histS, histD);
    scan_kernel<<<1, 1024, 0, stream>>>(histS, rowS, curS);
    scatter_kernel<<<(NE + 255) / 256, 256, 0, stream>>>(ea, src, dst, curS,
                                                         ea_p, src_s, dst_s);

    Params P;
    P.x = x; P.ea_p = ea_p; P.src_s = src_s; P.dst_s = dst_s;
    P.histD = histD; P.batch = batch;
    P.nn1_w1 = (const float*)d_in[4];  P.nn1_b1 = (const float*)d_in[5];
    P.nn1_w2 = (const float*)d_in[6];  P.nn1_b2 = (const float*)d_in[7];
    P.root1  = (const float*)d_in[8];  P.bias1  = (const float*)d_in[9];
    P.nn2_w1 = (const float*)d_in[10]; P.nn2_b1 = (const float*)d_in[11];
    P.nn2_w2 = (const float*)d_in[12]; P.nn2_b2 = (const float*)d_in[13];
    P.root2  = (const float*)d_in[14]; P.bias2  = (const float*)d_in[15];
    P.lin_w  = (const float*)d_in[16]; P.lin_b  = (const float*)d_in[17];
    P.Qp = Qp; P.Qb = Qb; P.agg = agg; P.h1 = h1; P.h2 = h2;
    P.pooled = pooled; P.gcnt = gcnt; P.out = (float*)d_out;

    // grid sized for guaranteed co-residency
    int maxBlocksPerCU = 0;
    hipError_t qerr = hipOccupancyMaxActiveBlocksPerMultiprocessor(
        &maxBlocksPerCU, mega_kernel, 256, 0);
    int cus = 0;
    hipDeviceGetAttribute(&cus, hipDeviceAttributeMultiprocessorCount, 0);
    int grid = (qerr == hipSuccess && maxBlocksPerCU > 0 && cus > 0)
                   ? maxBlocksPerCU * cus : 0;
    if (grid > 2048) grid = 2048;

    hipError_t lerr = hipErrorUnknown;
    if (grid > 0) {
        void* kp[] = { (void*)&P };
        lerr = hipLaunchCooperativeKernel(mega_kernel, dim3(grid), dim3(256),
                                          kp, 0, stream);
    }
    if (lerr != hipSuccess) {
        // fallback: identical phases as ordinary dispatches
        int g2 = 1024;
        for (int ph = 0; ph < 7; ++ph)
            phase_kernel<<<g2, 256, 0, stream>>>(P, ph);
    }
}

// Round 12
// 271.837 us; speedup vs baseline: 2.1513x; 2.1513x over previous
//
#include <hip/hip_runtime.h>
#include <hip/hip_bf16.h>
#include <stdint.h>

#define NN 10000
#define NE 250000
#define FEAT 16
#define EMB 32
#define HID 32
#define NV 12
#define EAD 9
#define NG 64
#define EPB 128   // edges per block in edge_agg
#define NCH 25    // nodes per block in computeQ_pack

__device__ __forceinline__ uint32_t bf16rne(float f) {
    uint32_t u = __float_as_uint(f);
    return (u + 0x7fffu + ((u >> 16) & 1u)) >> 16;
}
__device__ __forceinline__ float blo(uint32_t p) { return __uint_as_float(p << 16); }
__device__ __forceinline__ float bhi(uint32_t p) { return __uint_as_float(p & 0xffff0000u); }

__device__ __forceinline__ void atomic_pk_add_bf16(uint32_t* addr, uint32_t packed) {
    asm volatile("global_atomic_pk_add_bf16 %0, %1, off"
                 :: "v"((uint64_t)(uintptr_t)addr), "v"(packed) : "memory");
}

// ---------------------------------------------------------------------------
// src/dst degree histograms
// ---------------------------------------------------------------------------
__global__ void edge_stats_kernel(const int* __restrict__ src,
                                  const int* __restrict__ dst,
                                  int* __restrict__ histS,
                                  int* __restrict__ histD) {
    int e = blockIdx.x * blockDim.x + threadIdx.x;
    if (e >= NE) return;
    atomicAdd(&histS[src[e]], 1);
    atomicAdd(&histD[dst[e]], 1);
}

// ---------------------------------------------------------------------------
// Single-block exclusive scan of histS[NN] -> rowS[NN+1], curS[NN]
// ---------------------------------------------------------------------------
__global__ __launch_bounds__(1024) void scan_kernel(const int* __restrict__ hist,
                                                    int* __restrict__ rowStart,
                                                    int* __restrict__ cursor) {
    __shared__ int part[1024];
    int t = threadIdx.x;
    int base = t * 10;
    int local[10];
    int s = 0;
#pragma unroll
    for (int i = 0; i < 10; ++i) {
        int v = (base + i < NN) ? hist[base + i] : 0;
        local[i] = s;
        s += v;
    }
    part[t] = s;
    __syncthreads();
    for (int off = 1; off < 1024; off <<= 1) {
        int v = (t >= off) ? part[t - off] : 0;
        __syncthreads();
        part[t] += v;
        __syncthreads();
    }
    int pre = (t == 0) ? 0 : part[t - 1];
#pragma unroll
    for (int i = 0; i < 10; ++i) {
        if (base + i < NN) {
            int rs = pre + local[i];
            rowStart[base + i] = rs;
            cursor[base + i] = rs;
        }
    }
    if (t == 1023) rowStart[NN] = part[1023];
}

// ---------------------------------------------------------------------------
// Permute edges to src-sorted order (ea padded to 12 floats for float4 loads).
// ---------------------------------------------------------------------------
__global__ void scatter_kernel(const float* __restrict__ ea,
                               const int* __restrict__ src,
                               const int* __restrict__ dst,
                               int* __restrict__ cursorS,
                               float* __restrict__ ea_p,   // [E,12]
                               int* __restrict__ src_s,
                               int* __restrict__ dst_s) {
    int e = blockIdx.x * blockDim.x + threadIdx.x;
    if (e >= NE) return;
    int sv = src[e];
    int pos = atomicAdd(&cursorS[sv], 1);
    src_s[pos] = sv;
    dst_s[pos] = dst[e];
#pragma unroll
    for (int j = 0; j < 12; ++j)
        ea_p[(size_t)pos * 12 + j] = (j < EAD) ? ea[(size_t)e * EAD + j] : 0.f;
}

// ---------------------------------------------------------------------------
// Qp[n][kk][o] = packed bf16 pair of Q[n,2kk,o]/Q[n,2kk+1,o]; kk==0 lanes also
// emit the fp32 bias row Qb[n,o].
// ---------------------------------------------------------------------------
template <int DIN>
__global__ __launch_bounds__(256) void computeQ_pack_kernel(
    const float* __restrict__ h,    // [N,DIN]
    const float* __restrict__ w2,   // [32, DIN*32]
    const float* __restrict__ b2,   // [DIN*32]
    uint32_t* __restrict__ Qp,      // [N,16,32]
    float* __restrict__ Qb)         // [N,32]
{
    int t = threadIdx.x;
    int o = t & 31;
    int kk = (blockIdx.y * 256 + t) >> 5;  // 0..15
    float w0[DIN], w1r[DIN];
    const float* wa = w2 + (size_t)(2 * kk) * (DIN * 32) + o;
    const float* wb = w2 + (size_t)(2 * kk + 1) * (DIN * 32) + o;
#pragma unroll
    for (int i = 0; i < DIN; ++i) { w0[i] = wa[i * 32]; w1r[i] = wb[i * 32]; }

    int n0 = blockIdx.x * NCH;
    for (int j = 0; j < NCH; ++j) {
        int n = n0 + j;
        const float* hn = h + (size_t)n * DIN;
        float s0 = 0.f, s1 = 0.f;
#pragma unroll
        for (int i = 0; i < DIN; ++i) {
            float hv = hn[i];
            s0 += hv * w0[i];
            s1 += hv * w1r[i];
        }
        Qp[((size_t)n * 16 + kk) * 32 + o] = (bf16rne(s1) << 16) | bf16rne(s0);
        if (kk == 0) {
            float sb = 0.f;
#pragma unroll
            for (int i = 0; i < DIN; ++i) sb += hn[i] * b2[i * 32 + o];
            Qb[(size_t)n * 32 + o] = sb;
        }
    }
}

// ---------------------------------------------------------------------------
// Conv2's edge-MLP, precomputed (the BUBBLE between edge_agg1 and node1).
// Thread = (edge, c): computes hidden[4c..4c+3], packs 2 bf16-pair words.
// hid2[e*8+c] as uint2. Streaming writes only.
// ---------------------------------------------------------------------------
__global__ __launch_bounds__(256) void hidden_kernel(
    const float* __restrict__ ea_p,   // [E,12]
    const float* __restrict__ w1,     // [9,32]
    const float* __restrict__ b1,     // [32]
    uint2* __restrict__ hid2)         // [E,8]
{
    int t = threadIdx.x;
    int e = blockIdx.x * 32 + (t >> 3);
    int c = t & 7;
    if (e >= NE) return;
    const float4* eav = (const float4*)(ea_p + (size_t)e * 12);
    float4 a0 = eav[0], a1 = eav[1], a2 = eav[2];
    float hv[4];
#pragma unroll
    for (int kk = 0; kk < 4; ++kk) {
        int o = 4 * c + kk;
        float hs = b1[o];
        hs += a0.x * w1[0 * 32 + o] + a0.y * w1[1 * 32 + o]
            + a0.z * w1[2 * 32 + o] + a0.w * w1[3 * 32 + o];
        hs += a1.x * w1[4 * 32 + o] + a1.y * w1[5 * 32 + o]
            + a1.z * w1[6 * 32 + o] + a1.w * w1[7 * 32 + o];
        hs += a2.x * w1[8 * 32 + o];
        hv[kk] = fmaxf(hs, 0.f);
    }
    uint2 p;
    p.x = (bf16rne(hv[1]) << 16) | bf16rne(hv[0]);
    p.y = (bf16rne(hv[3]) << 16) | bf16rne(hv[2]);
    hid2[(size_t)e * 8 + c] = p;
}

// ---------------------------------------------------------------------------
// Edge messages + scatter-add via packed-bf16 atomics (4M instead of 8M).
// PRE=false: edge-MLP inline (conv1). PRE=true: hidden from hid2 (conv2).
// ---------------------------------------------------------------------------
template <bool PRE>
__global__ __launch_bounds__(256) void edge_agg_kernel(
    const float* __restrict__ ea_p,   // [E,12]
    const uint2* __restrict__ hid2,   // [E,8] (PRE only)
    const int* __restrict__ src_s,
    const int* __restrict__ dst_s,
    const float* __restrict__ w1,     // [9,32]
    const float* __restrict__ b1,     // [32]
    const uint32_t* __restrict__ Qp,  // [N,16,32]
    const float* __restrict__ Qb,     // [N,32]
    uint32_t* __restrict__ aggbf)     // [N,16] bf16 pairs
{
    __shared__ float s_hid[8][32];
    int t = threadIdx.x;
    int o = t & 31;
    int slot = t >> 5;

    float w1r[EAD];
    float b1r = 0.f;
    if (!PRE) {
#pragma unroll
        for (int j = 0; j < EAD; ++j) w1r[j] = w1[j * 32 + o];
        b1r = b1[o];
    }

    int base = blockIdx.x * EPB;
    int eend = min(base + EPB, NE);
    for (int e = base + slot; e < eend; e += 8) {
        if (!PRE) {
            const float4* eav = (const float4*)(ea_p + (size_t)e * 12);
            float4 a0 = eav[0], a1 = eav[1], a2 = eav[2];
            float hs = b1r;
            hs += a0.x * w1r[0] + a0.y * w1r[1] + a0.z * w1r[2] + a0.w * w1r[3];
            hs += a1.x * w1r[4] + a1.y * w1r[5] + a1.z * w1r[6] + a1.w * w1r[7];
            hs += a2.x * w1r[8];
            s_hid[slot][o] = fmaxf(hs, 0.f);
            __builtin_amdgcn_wave_barrier();
        }

        int sv = src_s[e];
        const uint32_t* q = Qp + (size_t)sv * 512 + o;
        float m = Qb[(size_t)sv * 32 + o];
        if (PRE) {
            const uint2* hp2 = hid2 + (size_t)e * 8;
#pragma unroll
            for (int c = 0; c < 8; ++c) {
                uint2 hp = hp2[c];               // same addr across lanes: broadcast
                uint32_t qa  = q[(2 * c) * 32];
                uint32_t qb2 = q[(2 * c + 1) * 32];
                m += blo(hp.x) * blo(qa) + bhi(hp.x) * bhi(qa)
                   + blo(hp.y) * blo(qb2) + bhi(hp.y) * bhi(qb2);
            }
        } else {
            const float4* hq = (const float4*)(&s_hid[slot][0]);
#pragma unroll
            for (int c = 0; c < 8; ++c) {
                float4 hv = hq[c];
                uint32_t qa  = q[(2 * c) * 32];
                uint32_t qb2 = q[(2 * c + 1) * 32];
                m += hv.x * blo(qa) + hv.y * bhi(qa)
                   + hv.z * blo(qb2) + hv.w * bhi(qb2);
            }
        }

        float m1 = __shfl_down(m, 1, 32);
        if (!(o & 1)) {
            uint32_t packed = (bf16rne(m1) << 16) | bf16rne(m);
            atomic_pk_add_bf16(aggbf + (size_t)dst_s[e] * 16 + (o >> 1), packed);
        }
        if (!PRE) __builtin_amdgcn_wave_barrier();
    }
}

// ---------------------------------------------------------------------------
// Node update, LDS-tiled (round-8 structure); reads packed-bf16 agg, re-zeros
// it inline for the next conv / next call.
// ---------------------------------------------------------------------------
template <int DIN, bool POOL>
__global__ __launch_bounds__(256) void node_update_kernel(
    uint32_t* __restrict__ aggbf,    // [N,16]
    const int* __restrict__ histD,
    const float* __restrict__ hin,
    const float* __restrict__ root,
    const float* __restrict__ bias,
    float* __restrict__ hout,
    float* __restrict__ pooled,
    const int* __restrict__ batch,
    float* __restrict__ gcnt)
{
    __shared__ float s_root[DIN][32];
    __shared__ float s_h[32][DIN + 1];
    int t = threadIdx.x;
    int n0 = blockIdx.x * 32;

    for (int i = t; i < DIN * 8; i += 256)
        ((float4*)&s_root[0][0])[i] = ((const float4*)root)[i];
    for (int idx = t; idx < 32 * DIN; idx += 256) {
        int nl = idx / DIN, i = idx - nl * DIN;
        int n = n0 + nl;
        s_h[nl][i] = (n < NN) ? hin[(size_t)n * DIN + i] : 0.f;
    }
    __syncthreads();

    int nl = t >> 3;
    int cg = t & 7;
    int n = n0 + nl;
    if (n >= NN) return;

    float inv = 1.0f / fmaxf((float)histD[n], 1.0f);
    uint2* ap = (uint2*)(aggbf + (size_t)n * 16 + cg * 2);
    uint2 a2 = *ap;
    *ap = make_uint2(0u, 0u);   // re-zero for next conv / next call

    float4 b4 = *(const float4*)(bias + cg * 4);
    float4 s;
    s.x = blo(a2.x) * inv + b4.x;
    s.y = bhi(a2.x) * inv + b4.y;
    s.z = blo(a2.y) * inv + b4.z;
    s.w = bhi(a2.y) * inv + b4.w;
#pragma unroll
    for (int i = 0; i < DIN; ++i) {
        float hv = s_h[nl][i];
        float4 r4 = *(const float4*)&s_root[i][cg * 4];
        s.x += hv * r4.x; s.y += hv * r4.y; s.z += hv * r4.z; s.w += hv * r4.w;
    }
    s.x = fmaxf(s.x, 0.f); s.y = fmaxf(s.y, 0.f);
    s.z = fmaxf(s.z, 0.f); s.w = fmaxf(s.w, 0.f);
    *(float4*)(hout + (size_t)n * 32 + cg * 4) = s;

    if (POOL) {
        int g = batch[n];
        atomicAdd(&pooled[g * 32 + cg * 4 + 0], s.x);
        atomicAdd(&pooled[g * 32 + cg * 4 + 1], s.y);
        atomicAdd(&pooled[g * 32 + cg * 4 + 2], s.z);
        atomicAdd(&pooled[g * 32 + cg * 4 + 3], s.w);
        if (cg == 0) atomicAdd(&gcnt[g], 1.0f);
    }
}

// ---------------------------------------------------------------------------
// pooled mean -> linear(32,12) -> log_softmax
// ---------------------------------------------------------------------------
__global__ void final_kernel(const float* __restrict__ pooled,
                             const float* __restrict__ gcnt,
                             const float* __restrict__ lin_w,
                             const float* __restrict__ lin_b,
                             float* __restrict__ out) {
    int g = threadIdx.x;
    if (g >= NG) return;
    float inv = 1.0f / fmaxf(gcnt[g], 1.0f);
    float p[HID];
#pragma unroll
    for (int h = 0; h < HID; ++h) p[h] = pooled[g * HID + h] * inv;
    float logits[NV];
    float mx = -1e30f;
#pragma unroll
    for (int v = 0; v < NV; ++v) {
        float s = lin_b[v];
#pragma unroll
        for (int h = 0; h < HID; ++h) s += p[h] * lin_w[h * NV + v];
        logits[v] = s;
        mx = fmaxf(mx, s);
    }
    float se = 0.f;
#pragma unroll
    for (int v = 0; v < NV; ++v) se += expf(logits[v] - mx);
    float lse = mx + logf(se);
#pragma unroll
    for (int v = 0; v < NV; ++v) out[g * NV + v] = logits[v] - lse;
}

// ---------------------------------------------------------------------------
extern "C" void kernel_launch(void* const* d_in, const int* in_sizes, int n_in,
                              void* d_out, int out_size, void* d_ws, size_t ws_size,
                              hipStream_t stream) {
    const float* x        = (const float*)d_in[0];
    const float* ea       = (const float*)d_in[1];
    const int*   eidx     = (const int*)d_in[2];
    const int*   batch    = (const int*)d_in[3];
    const float* nn1_w1   = (const float*)d_in[4];
    const float* nn1_b1   = (const float*)d_in[5];
    const float* nn1_w2   = (const float*)d_in[6];
    const float* nn1_b2   = (const float*)d_in[7];
    const float* root1    = (const float*)d_in[8];
    const float* bias1    = (const float*)d_in[9];
    const float* nn2_w1   = (const float*)d_in[10];
    const float* nn2_b1   = (const float*)d_in[11];
    const float* nn2_w2   = (const float*)d_in[12];
    const float* nn2_b2   = (const float*)d_in[13];
    const float* root2    = (const float*)d_in[14];
    const float* bias2    = (const float*)d_in[15];
    const float* lin_w    = (const float*)d_in[16];
    const float* lin_b    = (const float*)d_in[17];
    float* out = (float*)d_out;

    const int* src = eidx;
    const int* dst = eidx + NE;

    // workspace: big 16B-aligned arrays first, then ints, then zeroed region.
    char* base = (char*)d_ws;
    uint32_t* Qp    = (uint32_t*)base;                      // NN*512
    float* ea_p     = (float*)(Qp + (size_t)NN * 512);      // NE*12
    uint2* hid2     = (uint2*)(ea_p + (size_t)NE * 12);     // NE*8 uint2
    float* Qb       = (float*)(hid2 + (size_t)NE * 8);      // NN*32
    float* h1       = Qb + (size_t)NN * 32;                 // NN*32
    float* h2       = h1 + (size_t)NN * 32;                 // NN*32
    uint32_t* aggbf = (uint32_t*)(h2 + (size_t)NN * 32);    // NN*16 (zeroed)
    int*   src_s    = (int*)(aggbf + (size_t)NN * 16);      // NE
    int*   dst_s    = src_s + NE;                           // NE
    int*   rowS     = dst_s + NE;                           // NN+1
    int*   curS     = rowS + NN + 1;                        // NN
    int*   histS    = curS + NN;                            // NN (zeroed from here)
    int*   histD    = histS + NN;                           // NN
    float* pooled   = (float*)(histD + NN);                 // NG*32
    float* gcnt     = pooled + NG * 32;                     // NG
    size_t zero_bytes = ((size_t)NN * 2 + NG * 32 + NG) * 4;

    hipMemsetAsync(aggbf, 0, (size_t)NN * 16 * 4, stream);
    hipMemsetAsync(histS, 0, zero_bytes, stream);

    // ---- edge sort pre-pass (shared by both convs) ----
    edge_stats_kernel<<<(NE + 255) / 256, 256, 0, stream>>>(src, dst, histS, histD);
    scan_kernel<<<1, 1024, 0, stream>>>(histS, rowS, curS);
    scatter_kernel<<<(NE + 255) / 256, 256, 0, stream>>>(ea, src, dst, curS,
                                                         ea_p, src_s, dst_s);

    const int edge_grid = (NE + EPB - 1) / EPB;
    const int node_grid = (NN + 31) / 32;
    const int hid_grid  = (NE + 31) / 32;
    dim3 qgrid(NN / NCH, 2);

    // ---- conv1 ----
    computeQ_pack_kernel<FEAT><<<qgrid, 256, 0, stream>>>(x, nn1_w2, nn1_b2, Qp, Qb);
    edge_agg_kernel<false><<<edge_grid, 256, 0, stream>>>(
        ea_p, nullptr, src_s, dst_s, nn1_w1, nn1_b1, Qp, Qb, aggbf);
    // BUBBLE: conv2's edge-MLP (independent work) lets agg writeback drain
    hidden_kernel<<<hid_grid, 256, 0, stream>>>(ea_p, nn2_w1, nn2_b1, hid2);
    node_update_kernel<FEAT, false><<<node_grid, 256, 0, stream>>>(
        aggbf, histD, x, root1, bias1, h1, nullptr, nullptr, nullptr);

    // ---- conv2 ----
    computeQ_pack_kernel<EMB><<<qgrid, 256, 0, stream>>>(h1, nn2_w2, nn2_b2, Qp, Qb);
    edge_agg_kernel<true><<<edge_grid, 256, 0, stream>>>(
        ea_p, hid2, src_s, dst_s, nn2_w1, nn2_b1, Qp, Qb, aggbf);
    node_update_kernel<EMB, true><<<node_grid, 256, 0, stream>>>(
        aggbf, histD, h1, root2, bias2, h2, pooled, batch, gcnt);

    // ---- head ----
    final_kernel<<<1, 64, 0, stream>>>(pooled, gcnt, lin_w, lin_b, out);
}